// Round 6
// baseline (236.765 us; speedup 1.0000x reference)
//
#include <hip/hip_runtime.h>

#define TPB 256
#define RED_NB 2048

// Gaussian kernel, sigma=1.1, ksize=5 (precomputed, normalized)
#define K0 0.0707663f
#define K1 0.2444606f
#define K2 0.3695462f

typedef float f4 __attribute__((ext_vector_type(4)));

__device__ __forceinline__ f4 ld4(const float* __restrict__ p) { return *(const f4*)p; }

// reflect index (no edge repeat): j<0 -> -j, j>=n -> 2n-2-j
__device__ __forceinline__ int rref(int i, int n) {
    return i < 0 ? -i : (i >= n ? 2 * n - 2 - i : i);
}

// -------- trilinear resize (device helper), align_corners; compile-time sizes --------
template <int NIN, int M>
__device__ __forceinline__ void resize_one(const float* __restrict__ in,
                                           float* __restrict__ out, long idx) {
    constexpr float ratio = (float)((NIN - 1.0) / (M - 1.0));
    int z = (int)(idx % M); long r = idx / M;
    int y = (int)(r % M);   r /= M;
    int x = (int)(r % M);   int bc = (int)(r / M);

    float cx = (float)x * ratio, cy = (float)y * ratio, cz = (float)z * ratio;
    int x0 = min((int)cx, NIN - 1), y0 = min((int)cy, NIN - 1), z0 = min((int)cz, NIN - 1);
    float wx = cx - (float)x0, wy = cy - (float)y0, wz = cz - (float)z0;
    int x1 = min(x0 + 1, NIN - 1), y1 = min(y0 + 1, NIN - 1), z1 = min(z0 + 1, NIN - 1);

    const float* p = in + (long)bc * NIN * NIN * NIN;
    constexpr long sx = (long)NIN * NIN;
#define AT(xi, yi, zi) p[(long)(xi) * sx + (long)(yi) * NIN + (zi)]
    float c00 = AT(x0, y0, z0) * (1.f - wz) + AT(x0, y0, z1) * wz;
    float c01 = AT(x0, y1, z0) * (1.f - wz) + AT(x0, y1, z1) * wz;
    float c10 = AT(x1, y0, z0) * (1.f - wz) + AT(x1, y0, z1) * wz;
    float c11 = AT(x1, y1, z0) * (1.f - wz) + AT(x1, y1, z1) * wz;
#undef AT
    float c0 = c00 * (1.f - wy) + c01 * wy;
    float c1 = c10 * (1.f - wy) + c11 * wy;
    out[idx] = c0 * (1.f - wx) + c1 * wx;
}

// one kernel for all four resizes: ds1(3*S1), ds2(3*S2), is1(S1), is2(S2)
__global__ __launch_bounds__(TPB)
void resize_all_kernel(const float* __restrict__ D, const float* __restrict__ I,
                       float* __restrict__ ds1, float* __restrict__ ds2,
                       float* __restrict__ is1, float* __restrict__ is2,
                       long A, long Bn, long C, long Dn) {
    long idx = (long)blockIdx.x * blockDim.x + threadIdx.x;
    if (idx < A) { resize_one<160, 80>(D, ds1, idx); return; }
    idx -= A;
    if (idx < Bn) { resize_one<160, 40>(D, ds2, idx); return; }
    idx -= Bn;
    if (idx < C) { resize_one<160, 80>(I, is1, idx); return; }
    idx -= C;
    if (idx < Dn) { resize_one<160, 40>(I, is2, idx); }
}

// -------- gradient magnitude, f4 over z --------
template <int N>
__global__ __launch_bounds__(TPB)
void gradmag_v4(const float* __restrict__ img, float* __restrict__ g, int B) {
    constexpr int NZ4 = N / 4;
    constexpr long n2 = (long)N * N, n3 = n2 * N;
    long total = (long)B * N * N * NZ4;
    long idx = (long)blockIdx.x * blockDim.x + threadIdx.x;
    if (idx >= total) return;
    int z4 = (int)(idx % NZ4); long r = idx / NZ4;
    int y = (int)(r % N); r /= N;
    int x = (int)(r % N); int b = (int)(r / N);
    int z = z4 * 4;

    const float* base = img + (long)b * n3;
    const float* rowc = base + (long)x * n2 + (long)y * N;
    f4 cur = ld4(rowc + z);
    f4 prev = (z > 0) ? ld4(rowc + z - 4) : cur;
    f4 next = (z + 4 < N) ? ld4(rowc + z + 4) : cur;

    int xm = max(x - 1, 0), xp = min(x + 1, N - 1);
    int ym = max(y - 1, 0), yp = min(y + 1, N - 1);
    float hx = (x == 0 || x == N - 1) ? 1.f : 0.5f;
    float hy = (y == 0 || y == N - 1) ? 1.f : 0.5f;
    f4 rxp = ld4(base + (long)xp * n2 + (long)y * N + z);
    f4 rxm = ld4(base + (long)xm * n2 + (long)y * N + z);
    f4 ryp = ld4(base + (long)x * n2 + (long)yp * N + z);
    f4 rym = ld4(base + (long)x * n2 + (long)ym * N + z);

    f4 outv;
#pragma unroll
    for (int j = 0; j < 4; ++j) {
        float c = cur[j];
        float zmv = (j == 0) ? prev[3] : cur[(j == 0) ? 0 : j - 1];
        float zpv = (j == 3) ? next[0] : cur[(j == 3) ? 3 : j + 1];
        int gz = z + j;
        float dz = (gz == 0) ? (zpv - c) : ((gz == N - 1) ? (c - zmv) : 0.5f * (zpv - zmv));
        float dx = hx * (rxp[j] - rxm[j]);
        float dy = hy * (ryp[j] - rym[j]);
        outv[j] = sqrtf(dx * dx + dy * dy + dz * dz);
    }
    *(f4*)(g + (long)b * n3 + (long)x * n2 + (long)y * N + z) = outv;
}

// -------- fused blur x+y, 4 outputs per thread along y (column-sum reuse) --------
template <int N>
__global__ __launch_bounds__(TPB)
void blur_xy_y4(const float* __restrict__ in, float* __restrict__ out, int B) {
    constexpr int NZ4 = N / 4, NY4 = N / 4;
    constexpr long n2 = (long)N * N, n3 = n2 * N;
    long total = (long)B * N * NY4 * NZ4;
    long idx = (long)blockIdx.x * blockDim.x + threadIdx.x;
    if (idx >= total) return;
    int z4 = (int)(idx % NZ4); long r = idx / NZ4;
    int y4 = (int)(r % NY4); r /= NY4;
    int x = (int)(r % N); int b = (int)(r / N);
    int y0 = y4 * 4, z = z4 * 4;

    const float K[5] = {K0, K1, K2, K1, K0};
    const float* base = in + (long)b * n3 + z;

    f4 cs[8];
#pragma unroll
    for (int jj = 0; jj < 8; ++jj) cs[jj] = (f4){0.f, 0.f, 0.f, 0.f};

#pragma unroll
    for (int i = 0; i < 5; ++i) {
        int qx = rref(x + i - 2, N);
        const float* px = base + (long)qx * n2;
#pragma unroll
        for (int jj = 0; jj < 8; ++jj) {
            int qy = rref(y0 - 2 + jj, N);
            cs[jj] += K[i] * ld4(px + (long)qy * N);
        }
    }
    float* ob = out + (long)b * n3 + (long)x * n2 + z;
#pragma unroll
    for (int k = 0; k < 4; ++k) {
        f4 o = K0 * cs[k] + K1 * cs[k + 1] + K2 * cs[k + 2] + K1 * cs[k + 3] + K0 * cs[k + 4];
        *(f4*)(ob + (long)(y0 + k) * N) = o;
    }
}

// -------- Lame strain energy + in-register blur-z of igxy; z-chunk column walk --------
// Each thread: fixed (b,x,y), walks ZC4 f4-steps in z with register windows.
template <int N, int ZC4, int NCH>
__global__ __launch_bounds__(TPB)
void energy_walk(const float* __restrict__ def, const float* __restrict__ igxy,
                 float* __restrict__ partial, int B) {
    constexpr long n2 = (long)N * N, n3 = n2 * N;
    long idx = (long)blockIdx.x * blockDim.x + threadIdx.x;
    // idx = (((b*N + x)*N + y)*NCH + ch) ; grid is exact
    int chk = (int)(idx % NCH); long r = idx / NCH;
    int y = (int)(r % N); r /= N;
    int x = (int)(r % N); int b = (int)(r / N);
    int z0 = chk * ZC4 * 4;

    int xm = max(x - 1, 0), xp = min(x + 1, N - 1);
    int ym = max(y - 1, 0), yp = min(y + 1, N - 1);
    float hx = (x == 0 || x == N - 1) ? 1.f : 0.5f;
    float hy = (y == 0 || y == N - 1) ? 1.f : 0.5f;

    const float* base = def + (long)b * 3 * n3;
    const float* rc0 = base + (long)x * n2 + (long)y * N;          // channel 0 row
    long oxp = (long)(xp - x) * n2, oxm = (long)(xm - x) * n2;
    long oyp = (long)(yp - y) * N,  oym = (long)(ym - y) * N;
    const float* grow = igxy + (long)b * n3 + (long)x * n2 + (long)y * N;

    // init windows
    f4 P[3], C[3], Nx[3];
#pragma unroll
    for (int c = 0; c < 3; ++c) {
        const float* rc = rc0 + (long)c * n3;
        C[c] = ld4(rc + z0);
        P[c] = (z0 > 0) ? ld4(rc + z0 - 4) : C[c];
    }
    f4 gc = ld4(grow + z0);
    f4 gn = ld4(grow + z0 + 4);  // z0+8 <= N always (chunks have >=2 steps)
    f4 gp;
    if (z0 >= 4) gp = ld4(grow + z0 - 4);
    else { gp[0] = gn[0]; gp[1] = gc[3]; gp[2] = gc[2]; gp[3] = gc[1]; }

    float lsum = 0.f;
#pragma unroll
    for (int k = 0; k < ZC4; ++k) {
        int z = z0 + 4 * k;
        // next channel window + xy neighbors at this z
        f4 RXP[3], RXM[3], RYP[3], RYM[3];
#pragma unroll
        for (int c = 0; c < 3; ++c) {
            const float* rc = rc0 + (long)c * n3 + z;
            Nx[c] = (z + 8 <= N) ? ld4(rc + 4) : C[c];
            RXP[c] = ld4(rc + oxp);
            RXM[c] = ld4(rc + oxm);
            RYP[c] = ld4(rc + oyp);
            RYM[c] = ld4(rc + oym);
        }
        float gw[12];
#pragma unroll
        for (int i = 0; i < 4; ++i) { gw[i] = gp[i]; gw[4 + i] = gc[i]; gw[8 + i] = gn[i]; }

#pragma unroll
        for (int j = 0; j < 4; ++j) {
            int gz = z + j;
            float dX[3], dY[3], dZ[3];
#pragma unroll
            for (int c = 0; c < 3; ++c) {
                float cc = C[c][j];
                float zmv = (j == 0) ? P[c][3] : C[c][(j == 0) ? 0 : j - 1];
                float zpv = (j == 3) ? Nx[c][0] : C[c][(j == 3) ? 3 : j + 1];
                dZ[c] = (gz == 0) ? (zpv - cc)
                                  : ((gz == N - 1) ? (cc - zmv) : 0.5f * (zpv - zmv));
                dX[c] = hx * (RXP[c][j] - RXM[c][j]);
                dY[c] = hy * (RYP[c][j] - RYM[c][j]);
            }
            float igv = K0 * gw[2 + j] + K1 * gw[3 + j] + K2 * gw[4 + j]
                      + K1 * gw[5 + j] + K0 * gw[6 + j];
            float lam = fminf(fmaxf(1.0f + 2.0f * igv, 0.1f), 10.0f);
            float mu  = fminf(fmaxf(0.5f + 1.0f * igv, 0.1f), 10.0f);
            float wt  = 1.0f + 5.0f * igv;

            float Exx = dX[0], Eyy = dY[1], Ezz = dZ[2];
            float Exy = 0.5f * (dY[0] + dX[1]);
            float Exz = 0.5f * (dZ[0] + dX[2]);
            float Eyz = 0.5f * (dZ[1] + dY[2]);
            float tr = Exx + Eyy + Ezz;
            float e = 0.5f * lam * tr * tr +
                      mu * (Exx * Exx + Eyy * Eyy + Ezz * Ezz +
                            2.0f * (Exy * Exy + Exz * Exz + Eyz * Eyz));
            lsum += wt * e;
        }

        if (k + 1 < ZC4) {
            // advance windows
#pragma unroll
            for (int c = 0; c < 3; ++c) { P[c] = C[c]; C[c] = Nx[c]; }
            f4 ngp = gc, ngc = gn, ngn;
            if (z + 12 <= N) ngn = ld4(grow + z + 8);
            else { ngn[0] = ngc[2]; ngn[1] = ngc[1]; ngn[2] = ngc[0]; ngn[3] = ngp[3]; }
            gp = ngp; gc = ngc; gn = ngn;
        }
    }

    __shared__ float sm[TPB];
    sm[threadIdx.x] = lsum;
    __syncthreads();
    for (int s = TPB / 2; s > 0; s >>= 1) {
        if (threadIdx.x < s) sm[threadIdx.x] += sm[threadIdx.x + s];
        __syncthreads();
    }
    if (threadIdx.x == 0) partial[blockIdx.x] = sm[0];
}

// -------- combine scale partials + Jacobian penalty -> out[0] --------
__global__ __launch_bounds__(TPB)
void finalize_kernel(const float* __restrict__ partial,
                     const float* __restrict__ def, float* __restrict__ out) {
    __shared__ float sm[TPB];
    const float wts[3] = {1.0f, 0.5f, 0.25f};
    const float invcnt[3] = {1.0f / (2.0f * 160 * 160 * 160),
                             1.0f / (2.0f * 80 * 80 * 80),
                             1.0f / (2.0f * 40 * 40 * 40)};
    const int offs[3] = {0, 1600, 1800};
    const int cnts[3] = {1600, 200, 25};
    float acc = 0.f;
    for (int s = 0; s < 3; ++s) {
        float local = 0.f;
        for (int i = threadIdx.x; i < cnts[s]; i += TPB) local += partial[offs[s] + i];
        acc += wts[s] * invcnt[s] * local;
    }
    sm[threadIdx.x] = acc;
    __syncthreads();
    for (int s = TPB / 2; s > 0; s >>= 1) {
        if (threadIdx.x < s) sm[threadIdx.x] += sm[threadIdx.x + s];
        __syncthreads();
    }
    if (threadIdx.x == 0) {
        float jac = 0.f;
        const int n = 160;
        long n3 = (long)n * n * n;
        long ctr = ((long)80 * n + 80) * n + 80;
        for (int b = 0; b < 2; ++b) {
            const float* p = def + (long)b * 3 * n3;
            float J[3][3];
            for (int c = 0; c < 3; ++c) {
                const float* q = p + (long)c * n3 + ctr;
                J[c][0] = 0.5f * (q[(long)n * n] - q[-(long)n * n]);
                J[c][1] = 0.5f * (q[n] - q[-n]);
                J[c][2] = 0.5f * (q[1] - q[-1]);
            }
            float det = J[0][0] * (J[1][1] * J[2][2] - J[1][2] * J[2][1])
                      - J[0][1] * (J[1][0] * J[2][2] - J[1][2] * J[2][0])
                      + J[0][2] * (J[1][0] * J[2][1] - J[1][1] * J[2][0]);
            jac += fmaxf(-det, 0.f);
        }
        jac *= 0.5f; // mean over B=2
        out[0] = sm[0] + 0.1f * jac;
    }
}

extern "C" void kernel_launch(void* const* d_in, const int* in_sizes, int n_in,
                              void* d_out, int out_size, void* d_ws, size_t ws_size,
                              hipStream_t stream) {
    const float* D = (const float*)d_in[0];  // (2,3,160,160,160)
    const float* I = (const float*)d_in[1];  // (2,1,160,160,160)
    float* out = (float*)d_out;
    float* ws = (float*)d_ws;

    const int B = 2;
    const long S0 = (long)B * 160 * 160 * 160;
    const long S1 = (long)B * 80 * 80 * 80;
    const long S2 = (long)B * 40 * 40 * 40;

    // disjoint workspace layout
    float* partials = ws;                 // 3 * RED_NB (uses [0,1825))
    float* ds1 = partials + 3 * RED_NB;   // 3*S1
    float* is1 = ds1 + 3 * S1;            // S1
    float* g1  = is1 + S1;                // S1
    float* t1  = g1 + S1;                 // S1
    float* ds2 = t1 + S1;                 // 3*S2
    float* is2 = ds2 + 3 * S2;            // S2
    float* g2  = is2 + S2;                // S2
    float* t2  = g2 + S2;                 // S2
    float* g0  = t2 + S2;                 // S0
    float* t0  = g0 + S0;                 // S0

    // ---- all four resizes in ONE launch ----
    {
        long A = 3 * S1, Bn = 3 * S2, C = S1, Dn = S2;
        long tot = A + Bn + C + Dn;
        resize_all_kernel<<<(int)((tot + TPB - 1) / TPB), TPB, 0, stream>>>(
            D, I, ds1, ds2, is1, is2, A, Bn, C, Dn);
    }

    // ---- scale 0: n=160 ----
    {
        long total4 = S0 / 4;
        int blocks = (int)((total4 + TPB - 1) / TPB);
        gradmag_v4<160><<<blocks, TPB, 0, stream>>>(I, g0, B);
        long btot = (long)B * 160 * 40 * 40;
        blur_xy_y4<160><<<(int)((btot + TPB - 1) / TPB), TPB, 0, stream>>>(g0, t0, B);
        // threads = 2*160*160*8 = 409600 -> 1600 blocks exact
        energy_walk<160, 5, 8><<<1600, TPB, 0, stream>>>(D, t0, partials + 0, B);
    }

    // ---- scale 1: n=80 ----
    {
        long total4 = S1 / 4;
        int blocks = (int)((total4 + TPB - 1) / TPB);
        gradmag_v4<80><<<blocks, TPB, 0, stream>>>(is1, g1, B);
        long btot = (long)B * 80 * 20 * 20;
        blur_xy_y4<80><<<(int)((btot + TPB - 1) / TPB), TPB, 0, stream>>>(g1, t1, B);
        // threads = 2*80*80*4 = 51200 -> 200 blocks exact
        energy_walk<80, 5, 4><<<200, TPB, 0, stream>>>(ds1, t1, partials + 1600, B);
    }

    // ---- scale 2: n=40 ----
    {
        long total4 = S2 / 4;
        int blocks = (int)((total4 + TPB - 1) / TPB);
        gradmag_v4<40><<<blocks, TPB, 0, stream>>>(is2, g2, B);
        long btot = (long)B * 40 * 10 * 10;
        blur_xy_y4<40><<<(int)((btot + TPB - 1) / TPB), TPB, 0, stream>>>(g2, t2, B);
        // threads = 2*40*40*2 = 6400 -> 25 blocks exact
        energy_walk<40, 5, 2><<<25, TPB, 0, stream>>>(ds2, t2, partials + 1800, B);
    }

    finalize_kernel<<<1, TPB, 0, stream>>>(partials, D, out);
}

// Round 7
// 163.711 us; speedup vs baseline: 1.4462x; 1.4462x over previous
//
#include <hip/hip_runtime.h>

#define TPB 256

// Gaussian kernel, sigma=1.1, ksize=5 (precomputed, normalized)
#define K0 0.0707663f
#define K1 0.2444606f
#define K2 0.3695462f

// block ranges (B=2 fixed): energy/gradmag f4-units per scale
#define EB0 8000   // 2*160*160*40 / 256
#define EB1 1000   // 2*80*80*20  / 256
#define EB2 125    // 2*40*40*10  / 256
// blur y4-units per scale
#define BB0 2000   // 2*160*40*40 / 256
#define BB1 250    // 2*80*20*20  / 256
#define BB2 32     // ceil(2*40*10*10 / 256)

typedef float f4 __attribute__((ext_vector_type(4)));

__device__ __forceinline__ f4 ld4(const float* __restrict__ p) { return *(const f4*)p; }

// reflect index (no edge repeat): j<0 -> -j, j>=n -> 2n-2-j
__device__ __forceinline__ int rref(int i, int n) {
    return i < 0 ? -i : (i >= n ? 2 * n - 2 - i : i);
}

// -------- trilinear resize (device helper), align_corners --------
template <int NIN, int M>
__device__ __forceinline__ void resize_one(const float* __restrict__ in,
                                           float* __restrict__ out, long idx) {
    constexpr float ratio = (float)((NIN - 1.0) / (M - 1.0));
    int z = (int)(idx % M); long r = idx / M;
    int y = (int)(r % M);   r /= M;
    int x = (int)(r % M);   int bc = (int)(r / M);

    float cx = (float)x * ratio, cy = (float)y * ratio, cz = (float)z * ratio;
    int x0 = min((int)cx, NIN - 1), y0 = min((int)cy, NIN - 1), z0 = min((int)cz, NIN - 1);
    float wx = cx - (float)x0, wy = cy - (float)y0, wz = cz - (float)z0;
    int x1 = min(x0 + 1, NIN - 1), y1 = min(y0 + 1, NIN - 1), z1 = min(z0 + 1, NIN - 1);

    const float* p = in + (long)bc * NIN * NIN * NIN;
    constexpr long sx = (long)NIN * NIN;
#define AT(xi, yi, zi) p[(long)(xi) * sx + (long)(yi) * NIN + (zi)]
    float c00 = AT(x0, y0, z0) * (1.f - wz) + AT(x0, y0, z1) * wz;
    float c01 = AT(x0, y1, z0) * (1.f - wz) + AT(x0, y1, z1) * wz;
    float c10 = AT(x1, y0, z0) * (1.f - wz) + AT(x1, y0, z1) * wz;
    float c11 = AT(x1, y1, z0) * (1.f - wz) + AT(x1, y1, z1) * wz;
#undef AT
    float c0 = c00 * (1.f - wy) + c01 * wy;
    float c1 = c10 * (1.f - wy) + c11 * wy;
    out[idx] = c0 * (1.f - wx) + c1 * wx;
}

// one kernel for all four resizes: ds1(3*S1), ds2(3*S2), is1(S1), is2(S2)
__global__ __launch_bounds__(TPB)
void resize_all_kernel(const float* __restrict__ D, const float* __restrict__ I,
                       float* __restrict__ ds1, float* __restrict__ ds2,
                       float* __restrict__ is1, float* __restrict__ is2,
                       long A, long Bn, long C, long Dn) {
    long idx = (long)blockIdx.x * blockDim.x + threadIdx.x;
    if (idx < A) { resize_one<160, 80>(D, ds1, idx); return; }
    idx -= A;
    if (idx < Bn) { resize_one<160, 40>(D, ds2, idx); return; }
    idx -= Bn;
    if (idx < C) { resize_one<160, 80>(I, is1, idx); return; }
    idx -= C;
    if (idx < Dn) { resize_one<160, 40>(I, is2, idx); }
}

// -------- gradient magnitude, f4 over z (device) --------
template <int N>
__device__ __forceinline__ void gradmag_one(const float* __restrict__ img,
                                            float* __restrict__ g, long idx) {
    constexpr int NZ4 = N / 4;
    constexpr long n2 = (long)N * N, n3 = n2 * N;
    int z4 = (int)(idx % NZ4); long r = idx / NZ4;
    int y = (int)(r % N); r /= N;
    int x = (int)(r % N); int b = (int)(r / N);
    int z = z4 * 4;

    const float* base = img + (long)b * n3;
    const float* rowc = base + (long)x * n2 + (long)y * N;
    f4 cur = ld4(rowc + z);
    f4 prev = (z > 0) ? ld4(rowc + z - 4) : cur;
    f4 next = (z + 4 < N) ? ld4(rowc + z + 4) : cur;

    int xm = max(x - 1, 0), xp = min(x + 1, N - 1);
    int ym = max(y - 1, 0), yp = min(y + 1, N - 1);
    float hx = (x == 0 || x == N - 1) ? 1.f : 0.5f;
    float hy = (y == 0 || y == N - 1) ? 1.f : 0.5f;
    f4 rxp = ld4(base + (long)xp * n2 + (long)y * N + z);
    f4 rxm = ld4(base + (long)xm * n2 + (long)y * N + z);
    f4 ryp = ld4(base + (long)x * n2 + (long)yp * N + z);
    f4 rym = ld4(base + (long)x * n2 + (long)ym * N + z);

    f4 outv;
#pragma unroll
    for (int j = 0; j < 4; ++j) {
        float c = cur[j];
        float zmv = (j == 0) ? prev[3] : cur[(j == 0) ? 0 : j - 1];
        float zpv = (j == 3) ? next[0] : cur[(j == 3) ? 3 : j + 1];
        int gz = z + j;
        float dz = (gz == 0) ? (zpv - c) : ((gz == N - 1) ? (c - zmv) : 0.5f * (zpv - zmv));
        float dx = hx * (rxp[j] - rxm[j]);
        float dy = hy * (ryp[j] - rym[j]);
        outv[j] = sqrtf(dx * dx + dy * dy + dz * dz);
    }
    *(f4*)(g + (long)b * n3 + (long)x * n2 + (long)y * N + z) = outv;
}

__global__ __launch_bounds__(TPB)
void gradmag_all(const float* __restrict__ I0, const float* __restrict__ is1,
                 const float* __restrict__ is2, float* __restrict__ g0,
                 float* __restrict__ g1, float* __restrict__ g2) {
    int blk = blockIdx.x;
    if (blk < EB0)            gradmag_one<160>(I0,  g0, (long)blk * TPB + threadIdx.x);
    else if (blk < EB0 + EB1) gradmag_one<80> (is1, g1, (long)(blk - EB0) * TPB + threadIdx.x);
    else                      gradmag_one<40> (is2, g2, (long)(blk - EB0 - EB1) * TPB + threadIdx.x);
}

// -------- fused blur x+y, 4 outputs per thread along y (device) --------
template <int N>
__device__ __forceinline__ void blur_one(const float* __restrict__ in,
                                         float* __restrict__ out, long idx) {
    constexpr int NZ4 = N / 4, NY4 = N / 4;
    constexpr long n2 = (long)N * N, n3 = n2 * N;
    int z4 = (int)(idx % NZ4); long r = idx / NZ4;
    int y4 = (int)(r % NY4); r /= NY4;
    int x = (int)(r % N); int b = (int)(r / N);
    int y0 = y4 * 4, z = z4 * 4;

    const float K[5] = {K0, K1, K2, K1, K0};
    const float* base = in + (long)b * n3 + z;

    f4 cs[8];
#pragma unroll
    for (int jj = 0; jj < 8; ++jj) cs[jj] = (f4){0.f, 0.f, 0.f, 0.f};

#pragma unroll
    for (int i = 0; i < 5; ++i) {
        int qx = rref(x + i - 2, N);
        const float* px = base + (long)qx * n2;
#pragma unroll
        for (int jj = 0; jj < 8; ++jj) {
            int qy = rref(y0 - 2 + jj, N);
            cs[jj] += K[i] * ld4(px + (long)qy * N);
        }
    }
    float* ob = out + (long)b * n3 + (long)x * n2 + z;
#pragma unroll
    for (int k = 0; k < 4; ++k) {
        f4 o = K0 * cs[k] + K1 * cs[k + 1] + K2 * cs[k + 2] + K1 * cs[k + 3] + K0 * cs[k + 4];
        *(f4*)(ob + (long)(y0 + k) * N) = o;
    }
}

__global__ __launch_bounds__(TPB)
void blur_all(const float* __restrict__ g0, const float* __restrict__ g1,
              const float* __restrict__ g2, float* __restrict__ t0,
              float* __restrict__ t1, float* __restrict__ t2) {
    int blk = blockIdx.x;
    if (blk < BB0)            blur_one<160>(g0, t0, (long)blk * TPB + threadIdx.x);
    else if (blk < BB0 + BB1) blur_one<80> (g1, t1, (long)(blk - BB0) * TPB + threadIdx.x);
    else {
        long idx = (long)(blk - BB0 - BB1) * TPB + threadIdx.x;
        if (idx < (long)2 * 40 * 10 * 10) blur_one<40>(g2, t2, idx);
    }
}

// -------- Lame strain energy + in-register blur-z of igxy (device, per f4) --------
template <int N>
__device__ __forceinline__ float energy_one(const float* __restrict__ def,
                                            const float* __restrict__ igxy, long idx) {
    constexpr int NZ4 = N / 4;
    constexpr long n2 = (long)N * N, n3 = n2 * N;
    int z4 = (int)(idx % NZ4); long r = idx / NZ4;
    int y = (int)(r % N); r /= N;
    int x = (int)(r % N); int b = (int)(r / N);
    int z = z4 * 4;

    int xm = max(x - 1, 0), xp = min(x + 1, N - 1);
    int ym = max(y - 1, 0), yp = min(y + 1, N - 1);
    float hx = (x == 0 || x == N - 1) ? 1.f : 0.5f;
    float hy = (y == 0 || y == N - 1) ? 1.f : 0.5f;

    const float* base = def + (long)b * 3 * n3;
    long sp = (long)x * n2 + (long)y * N + z;

    f4 CC[3], CP[3], CN[3], RXP[3], RXM[3], RYP[3], RYM[3];
#pragma unroll
    for (int c = 0; c < 3; ++c) {
        const float* rc = base + (long)c * n3 + sp;
        CC[c] = ld4(rc);
        CP[c] = (z > 0) ? ld4(rc - 4) : CC[c];
        CN[c] = (z + 4 < N) ? ld4(rc + 4) : CC[c];
        RXP[c] = ld4(base + (long)c * n3 + (long)xp * n2 + (long)y * N + z);
        RXM[c] = ld4(base + (long)c * n3 + (long)xm * n2 + (long)y * N + z);
        RYP[c] = ld4(base + (long)c * n3 + (long)x * n2 + (long)yp * N + z);
        RYM[c] = ld4(base + (long)c * n3 + (long)x * n2 + (long)ym * N + z);
    }

    // z-blur window of igxy (reflect boundary)
    const float* growc = igxy + (long)b * n3 + (long)x * n2 + (long)y * N;
    f4 gcur = ld4(growc + z);
    f4 gprev, gnext;
    if (z >= 4) gprev = ld4(growc + z - 4);
    else { gprev[0] = growc[4]; gprev[1] = growc[3]; gprev[2] = growc[2]; gprev[3] = growc[1]; }
    if (z + 8 <= N) gnext = ld4(growc + z + 4);
    else { gnext[0] = growc[N - 2]; gnext[1] = growc[N - 3]; gnext[2] = growc[N - 4]; gnext[3] = growc[N - 5]; }
    float gw[12];
#pragma unroll
    for (int i = 0; i < 4; ++i) { gw[i] = gprev[i]; gw[4 + i] = gcur[i]; gw[8 + i] = gnext[i]; }

    float lsum = 0.f;
#pragma unroll
    for (int j = 0; j < 4; ++j) {
        int gz = z + j;
        float dX[3], dY[3], dZ[3];
#pragma unroll
        for (int c = 0; c < 3; ++c) {
            float cc = CC[c][j];
            float zmv = (j == 0) ? CP[c][3] : CC[c][(j == 0) ? 0 : j - 1];
            float zpv = (j == 3) ? CN[c][0] : CC[c][(j == 3) ? 3 : j + 1];
            dZ[c] = (gz == 0) ? (zpv - cc)
                              : ((gz == N - 1) ? (cc - zmv) : 0.5f * (zpv - zmv));
            dX[c] = hx * (RXP[c][j] - RXM[c][j]);
            dY[c] = hy * (RYP[c][j] - RYM[c][j]);
        }
        float igv = K0 * gw[2 + j] + K1 * gw[3 + j] + K2 * gw[4 + j]
                  + K1 * gw[5 + j] + K0 * gw[6 + j];
        float lam = fminf(fmaxf(1.0f + 2.0f * igv, 0.1f), 10.0f);
        float mu  = fminf(fmaxf(0.5f + 1.0f * igv, 0.1f), 10.0f);
        float wt  = 1.0f + 5.0f * igv;

        float Exx = dX[0], Eyy = dY[1], Ezz = dZ[2];
        float Exy = 0.5f * (dY[0] + dX[1]);
        float Exz = 0.5f * (dZ[0] + dX[2]);
        float Eyz = 0.5f * (dZ[1] + dY[2]);
        float tr = Exx + Eyy + Ezz;
        float e = 0.5f * lam * tr * tr +
                  mu * (Exx * Exx + Eyy * Eyy + Ezz * Ezz +
                        2.0f * (Exy * Exy + Exz * Exz + Eyz * Eyz));
        lsum += wt * e;
    }
    return lsum;
}

__global__ __launch_bounds__(TPB)
void energy_all(const float* __restrict__ D, const float* __restrict__ ds1,
                const float* __restrict__ ds2, const float* __restrict__ t0,
                const float* __restrict__ t1, const float* __restrict__ t2,
                float* __restrict__ partial) {
    int blk = blockIdx.x;
    float lsum;
    if (blk < EB0)            lsum = energy_one<160>(D,   t0, (long)blk * TPB + threadIdx.x);
    else if (blk < EB0 + EB1) lsum = energy_one<80> (ds1, t1, (long)(blk - EB0) * TPB + threadIdx.x);
    else                      lsum = energy_one<40> (ds2, t2, (long)(blk - EB0 - EB1) * TPB + threadIdx.x);

    __shared__ float sm[TPB];
    sm[threadIdx.x] = lsum;
    __syncthreads();
    for (int s = TPB / 2; s > 0; s >>= 1) {
        if (threadIdx.x < s) sm[threadIdx.x] += sm[threadIdx.x + s];
        __syncthreads();
    }
    if (threadIdx.x == 0) partial[blk] = sm[0];
}

// -------- combine scale partials + Jacobian penalty -> out[0] --------
__global__ __launch_bounds__(TPB)
void finalize_kernel(const float* __restrict__ partial,
                     const float* __restrict__ def, float* __restrict__ out) {
    __shared__ float sm[TPB];
    const float wts[3] = {1.0f, 0.5f, 0.25f};
    const float invcnt[3] = {1.0f / (2.0f * 160 * 160 * 160),
                             1.0f / (2.0f * 80 * 80 * 80),
                             1.0f / (2.0f * 40 * 40 * 40)};
    const int offs[3] = {0, EB0, EB0 + EB1};
    const int cnts[3] = {EB0, EB1, EB2};
    float acc = 0.f;
    for (int s = 0; s < 3; ++s) {
        float local = 0.f;
        for (int i = threadIdx.x; i < cnts[s]; i += TPB) local += partial[offs[s] + i];
        acc += wts[s] * invcnt[s] * local;
    }
    sm[threadIdx.x] = acc;
    __syncthreads();
    for (int s = TPB / 2; s > 0; s >>= 1) {
        if (threadIdx.x < s) sm[threadIdx.x] += sm[threadIdx.x + s];
        __syncthreads();
    }
    if (threadIdx.x == 0) {
        float jac = 0.f;
        const int n = 160;
        long n3 = (long)n * n * n;
        long ctr = ((long)80 * n + 80) * n + 80;
        for (int b = 0; b < 2; ++b) {
            const float* p = def + (long)b * 3 * n3;
            float J[3][3];
            for (int c = 0; c < 3; ++c) {
                const float* q = p + (long)c * n3 + ctr;
                J[c][0] = 0.5f * (q[(long)n * n] - q[-(long)n * n]);
                J[c][1] = 0.5f * (q[n] - q[-n]);
                J[c][2] = 0.5f * (q[1] - q[-1]);
            }
            float det = J[0][0] * (J[1][1] * J[2][2] - J[1][2] * J[2][1])
                      - J[0][1] * (J[1][0] * J[2][2] - J[1][2] * J[2][0])
                      + J[0][2] * (J[1][0] * J[2][1] - J[1][1] * J[2][0]);
            jac += fmaxf(-det, 0.f);
        }
        jac *= 0.5f; // mean over B=2
        out[0] = sm[0] + 0.1f * jac;
    }
}

extern "C" void kernel_launch(void* const* d_in, const int* in_sizes, int n_in,
                              void* d_out, int out_size, void* d_ws, size_t ws_size,
                              hipStream_t stream) {
    const float* D = (const float*)d_in[0];  // (2,3,160,160,160)
    const float* I = (const float*)d_in[1];  // (2,1,160,160,160)
    float* out = (float*)d_out;
    float* ws = (float*)d_ws;

    const int B = 2;
    const long S0 = (long)B * 160 * 160 * 160;
    const long S1 = (long)B * 80 * 80 * 80;
    const long S2 = (long)B * 40 * 40 * 40;

    // disjoint workspace layout
    float* partials = ws;                 // 9216 (uses [0, 9125))
    float* ds1 = partials + 9216;         // 3*S1
    float* is1 = ds1 + 3 * S1;            // S1
    float* g1  = is1 + S1;                // S1
    float* t1  = g1 + S1;                 // S1
    float* ds2 = t1 + S1;                 // 3*S2
    float* is2 = ds2 + 3 * S2;            // S2
    float* g2  = is2 + S2;                // S2
    float* t2  = g2 + S2;                 // S2
    float* g0  = t2 + S2;                 // S0
    float* t0  = g0 + S0;                 // S0

    // 1) all four resizes
    {
        long A = 3 * S1, Bn = 3 * S2, C = S1, Dn = S2;
        long tot = A + Bn + C + Dn;
        resize_all_kernel<<<(int)((tot + TPB - 1) / TPB), TPB, 0, stream>>>(
            D, I, ds1, ds2, is1, is2, A, Bn, C, Dn);
    }
    // 2) gradmag, all scales
    gradmag_all<<<EB0 + EB1 + EB2, TPB, 0, stream>>>(I, is1, is2, g0, g1, g2);
    // 3) blur x+y, all scales
    blur_all<<<BB0 + BB1 + BB2, TPB, 0, stream>>>(g0, g1, g2, t0, t1, t2);
    // 4) energy (+ in-register z-blur), all scales
    energy_all<<<EB0 + EB1 + EB2, TPB, 0, stream>>>(D, ds1, ds2, t0, t1, t2, partials);
    // 5) finalize
    finalize_kernel<<<1, TPB, 0, stream>>>(partials, D, out);
}